// Round 2
// baseline (2640.468 us; speedup 1.0000x reference)
//
#include <hip/hip_runtime.h>

#define HW_N 16384   // 128*128 pixels
#define CCH  256     // channels
#define KTOP 20
#define TP   64      // pixel tile
#define TN   64      // candidate tile
#define KC   32      // K chunk
#define SLICE 4096   // candidates per block-slot (fg=4096, bg=3*4096)
#define NFG  4096
#define NBG  12288

// ---------------- norms ----------------

// inv_ns[p] = 1/max(||s[:,p]||,eps). s layout [C][HW]; lanes vary p -> coalesced.
__global__ void s_norm_kernel(const float* __restrict__ s, float* __restrict__ inv_ns) {
    int p = blockIdx.x * blockDim.x + threadIdx.x;
    float acc = 0.f;
#pragma unroll 8
    for (int c = 0; c < CCH; ++c) {
        float v = s[(size_t)c * HW_N + p];
        acc = fmaf(v, v, acc);
    }
    inv_ns[p] = 1.0f / fmaxf(sqrtf(acc), 1e-12f);
}

// one wave per row (256 contiguous floats), float4 + shuffle reduce
__global__ void c_norm_kernel(const float* __restrict__ feats, float* __restrict__ inv_nc, int nrows) {
    int row  = blockIdx.x * 4 + (threadIdx.x >> 6);
    int lane = threadIdx.x & 63;
    if (row >= nrows) return;
    const float4 v = reinterpret_cast<const float4*>(feats + (size_t)row * CCH)[lane];
    float acc = v.x*v.x + v.y*v.y + v.z*v.z + v.w*v.w;
#pragma unroll
    for (int off = 32; off > 0; off >>= 1) acc += __shfl_down(acc, off);
    if (lane == 0) inv_nc[row] = 1.0f / fmaxf(sqrtf(acc), 1e-12f);
}

// ---------------- main fused GEMM + topK ----------------
// grid: (HW_N/TP, 4). slot 0 = fg; slots 1..3 = bg thirds. Each block: 64 px x 4096 cands.
// partial: [4][HW_N][KTOP]
__global__ __launch_bounds__(256, 4) void score_kernel(
    const float* __restrict__ s,          // [256][16384]
    const float* __restrict__ fg,         // [4096][256]
    const float* __restrict__ bg,         // [12288][256]
    const float* __restrict__ inv_nc_fg,
    const float* __restrict__ inv_nc_bg,
    float* __restrict__ partial)
{
    __shared__ float sA[KC][TP + 4];      // sA[kk][p] = s[c0+kk][p0+p], stride 68
    __shared__ float sB[KC][TN + 4];      // sB[kk][n] = cand[n0+n][c0+kk]
    __shared__ float sSim[TN][TP + 4];    // sim[n][p]
    __shared__ float sInv[TN];

    const int T  = threadIdx.x;
    const int tx = T & 15;                // candidate group (4 cands)
    const int ty = T >> 4;                // pixel group (4 px)
    const int p0 = blockIdx.x * TP;
    const int slot = blockIdx.y;

    const float* cbase;
    const float* invc;
    if (slot == 0) { cbase = fg; invc = inv_nc_fg; }
    else { cbase = bg + (size_t)(slot - 1) * SLICE * CCH; invc = inv_nc_bg + (slot - 1) * SLICE; }

    float lst[KTOP];
#pragma unroll
    for (int i = 0; i < KTOP; ++i) lst[i] = -1e30f;

    // staging maps
    const int a_kk  = T >> 3;             // 0..31
    const int a_pos = (T & 7) * 4;        // 0..28
    const int b_row = T >> 2;             // 0..63
    const int b_kg  = (T & 3) * 4;        // 0,4,8,12

    for (int n0 = 0; n0 < SLICE; n0 += TN) {
        if (T < TN) sInv[T] = invc[n0 + T];
        float acc[4][4];
#pragma unroll
        for (int i = 0; i < 4; ++i)
#pragma unroll
            for (int j = 0; j < 4; ++j) acc[i][j] = 0.f;

        for (int c0 = 0; c0 < CCH; c0 += KC) {
            __syncthreads();              // prev inner reads / prev scan done
            // stage A (coalesced over p)
            {
                const float* src = s + (size_t)(c0 + a_kk) * HW_N + p0 + a_pos;
                float4 v0 = *reinterpret_cast<const float4*>(src);
                float4 v1 = *reinterpret_cast<const float4*>(src + 32);
                *reinterpret_cast<float4*>(&sA[a_kk][a_pos])      = v0;
                *reinterpret_cast<float4*>(&sA[a_kk][a_pos + 32]) = v1;
            }
            // stage B transposed
            {
                const float* src = cbase + (size_t)(n0 + b_row) * CCH + c0 + b_kg;
                float4 v0 = *reinterpret_cast<const float4*>(src);
                float4 v1 = *reinterpret_cast<const float4*>(src + 16);
                sB[b_kg + 0 ][b_row] = v0.x;
                sB[b_kg + 1 ][b_row] = v0.y;
                sB[b_kg + 2 ][b_row] = v0.z;
                sB[b_kg + 3 ][b_row] = v0.w;
                sB[b_kg + 16][b_row] = v1.x;
                sB[b_kg + 17][b_row] = v1.y;
                sB[b_kg + 18][b_row] = v1.z;
                sB[b_kg + 19][b_row] = v1.w;
            }
            __syncthreads();
#pragma unroll
            for (int kk = 0; kk < KC; ++kk) {
                float4 a = *reinterpret_cast<const float4*>(&sA[kk][ty * 4]);
                float4 b = *reinterpret_cast<const float4*>(&sB[kk][tx * 4]);
                float av[4] = {a.x, a.y, a.z, a.w};
                float bv[4] = {b.x, b.y, b.z, b.w};
#pragma unroll
                for (int i = 0; i < 4; ++i)
#pragma unroll
                    for (int j = 0; j < 4; ++j)
                        acc[i][j] = fmaf(av[i], bv[j], acc[i][j]);
            }
        }
        __syncthreads();                  // inner reads done before sim write
        // epilogue: apply candidate norm, write sim[n][p]
#pragma unroll
        for (int j = 0; j < 4; ++j) {
            float iv = sInv[tx * 4 + j];
            float4 w;
            w.x = acc[0][j] * iv; w.y = acc[1][j] * iv;
            w.z = acc[2][j] * iv; w.w = acc[3][j] * iv;
            *reinterpret_cast<float4*>(&sSim[tx * 4 + j][ty * 4]) = w;
        }
        __syncthreads();
        // scan: thread T<64 owns pixel p0+T, maintains sorted top-20 in regs
        if (T < TP) {
            for (int n = 0; n < TN; ++n) {
                float v = sSim[n][T];
                if (v > lst[KTOP - 1]) {
                    lst[KTOP - 1] = v;
#pragma unroll
                    for (int i = KTOP - 1; i >= 1; --i) {
                        if (lst[i] > lst[i - 1]) { float t = lst[i - 1]; lst[i - 1] = lst[i]; lst[i] = t; }
                    }
                }
            }
        }
    }
    if (T < TP) {
        float* dst = partial + ((size_t)slot * HW_N + p0 + T) * KTOP;
#pragma unroll
        for (int i = 0; i < KTOP; ++i) dst[i] = lst[i];
    }
}

// ---------------- merge partials -> output ----------------
__global__ void merge_kernel(const float* __restrict__ partial,
                             const float* __restrict__ inv_ns,
                             float* __restrict__ out) {
    int idx  = blockIdx.x * blockDim.x + threadIdx.x;   // 0..32767
    int coll = idx >> 14;                               // 0=fg, 1=bg
    int p    = idx & (HW_N - 1);
    float lst[KTOP];
#pragma unroll
    for (int i = 0; i < KTOP; ++i) lst[i] = -1e30f;
    int s0 = (coll == 0) ? 0 : 1;
    int s1 = (coll == 0) ? 1 : 4;
    for (int sl = s0; sl < s1; ++sl) {
        const float* src = partial + ((size_t)sl * HW_N + p) * KTOP;
#pragma unroll
        for (int i = 0; i < KTOP; ++i) {
            float v = src[i];
            if (v > lst[KTOP - 1]) {
                lst[KTOP - 1] = v;
#pragma unroll
                for (int k = KTOP - 1; k >= 1; --k)
                    if (lst[k] > lst[k - 1]) { float t = lst[k - 1]; lst[k - 1] = lst[k]; lst[k] = t; }
            }
        }
    }
    float sum = 0.f;
#pragma unroll
    for (int i = 0; i < KTOP; ++i) sum += lst[i];
    out[idx] = (sum / (float)KTOP) * inv_ns[p];
}

// ---------------- launch ----------------
extern "C" void kernel_launch(void* const* d_in, const int* in_sizes, int n_in,
                              void* d_out, int out_size, void* d_ws, size_t ws_size,
                              hipStream_t stream) {
    const float* s_feat = (const float*)d_in[0];   // [1,256,128,128]
    const float* fg     = (const float*)d_in[1];   // [4096,256]
    const float* bg     = (const float*)d_in[2];   // [12288,256]
    float* out = (float*)d_out;                    // [2][128][128]

    float* partial = (float*)d_ws;                 // 4*16384*20 floats = 5.24 MB
    float* inv_ns  = partial + (size_t)4 * HW_N * KTOP;
    float* inv_fg  = inv_ns + HW_N;
    float* inv_bg  = inv_fg + NFG;

    s_norm_kernel<<<HW_N / 256, 256, 0, stream>>>(s_feat, inv_ns);
    c_norm_kernel<<<NFG / 4, 256, 0, stream>>>(fg, inv_fg, NFG);
    c_norm_kernel<<<NBG / 4, 256, 0, stream>>>(bg, inv_bg, NBG);

    dim3 grid(HW_N / TP, 4);
    score_kernel<<<grid, 256, 0, stream>>>(s_feat, fg, bg, inv_fg, inv_bg, partial);

    merge_kernel<<<(2 * HW_N) / 256, 256, 0, stream>>>(partial, inv_ns, out);
}

// Round 4
// 709.520 us; speedup vs baseline: 3.7215x; 3.7215x over previous
//
#include <hip/hip_runtime.h>

#define HW_N 16384   // 128*128 pixels
#define CCH  256     // channels
#define KTOP 20
#define NFG  4096
#define NBG  12288
#define NTOT 16384   // fg+bg concatenated rows
#define BPX  64      // pixels per block
#define BCAND 256    // candidates per tile
#define KC   64      // K chunk (channels per B stage)
#define SLICE 4096   // candidates per slot
#define TILES (SLICE / BCAND)   // 16

typedef __attribute__((ext_vector_type(8))) short short8;      // 8 bf16 (4 VGPRs)
typedef __attribute__((ext_vector_type(8))) _Float16 half8;
typedef __attribute__((ext_vector_type(4))) float f32x4;

__device__ __forceinline__ unsigned short f2bf(float v) {
    union { float f; unsigned int u; } c; c.f = v;
    unsigned int r = c.u + 0x7fffu + ((c.u >> 16) & 1u);       // RNE
    return (unsigned short)(r >> 16);
}

__device__ __forceinline__ void ins20(float (&lst)[KTOP], float v) {
    if (v > lst[KTOP - 1]) {
        lst[KTOP - 1] = v;
#pragma unroll
        for (int i = KTOP - 1; i >= 1; --i) {
            float a = lst[i - 1], b = lst[i];
            lst[i - 1] = fmaxf(a, b);
            lst[i]     = fminf(a, b);
        }
    }
}

// ---------- prep: transpose + L2-normalize s -> sn_bf16 [16384][256] ----------
__global__ __launch_bounds__(256) void s_prep_kernel(const float* __restrict__ s,
                                                     unsigned short* __restrict__ sn) {
    __shared__ float T[64][261];              // pad 261: <=2-way banks both phases
    const int t  = threadIdx.x;
    const int p0 = blockIdx.x * 64;
    // load [256ch][64px] tile, coalesced over px
#pragma unroll
    for (int pass = 0; pass < 16; ++pass) {
        int c = pass * 16 + (t >> 4);
        float4 v = *reinterpret_cast<const float4*>(&s[(size_t)c * HW_N + p0 + (t & 15) * 4]);
        int px = (t & 15) * 4;
        T[px + 0][c] = v.x; T[px + 1][c] = v.y; T[px + 2][c] = v.z; T[px + 3][c] = v.w;
    }
    __syncthreads();
    const int px = t >> 2, q = t & 3;         // 4 threads per pixel row
    float sum = 0.f;
#pragma unroll 8
    for (int i = 0; i < 64; ++i) { float v = T[px][q * 64 + i]; sum = fmaf(v, v, sum); }
    sum += __shfl_xor(sum, 1);
    sum += __shfl_xor(sum, 2);
    const float scale = 1.0f / fmaxf(sqrtf(sum), 1e-12f);
    uint4* dst = reinterpret_cast<uint4*>(&sn[(size_t)(p0 + px) * CCH + q * 64]);
#pragma unroll
    for (int g = 0; g < 8; ++g) {
        unsigned int vv[4];
#pragma unroll
        for (int h = 0; h < 4; ++h) {
            float a = T[px][q * 64 + g * 8 + h * 2 + 0] * scale;
            float b = T[px][q * 64 + g * 8 + h * 2 + 1] * scale;
            vv[h] = (unsigned)f2bf(a) | ((unsigned)f2bf(b) << 16);
        }
        uint4 wv; wv.x = vv[0]; wv.y = vv[1]; wv.z = vv[2]; wv.w = vv[3];
        dst[g] = wv;
    }
}

// ---------- prep: L2-normalize fg|bg -> cn_bf16 [16384][256] ----------
__global__ __launch_bounds__(256) void c_prep_kernel(const float* __restrict__ fg,
                                                     const float* __restrict__ bg,
                                                     unsigned short* __restrict__ cn) {
    const int row  = blockIdx.x * 4 + (threadIdx.x >> 6);
    const int lane = threadIdx.x & 63;
    const float* src = (row < NFG) ? &fg[(size_t)row * CCH] : &bg[(size_t)(row - NFG) * CCH];
    float4 v = reinterpret_cast<const float4*>(src)[lane];
    float sum = v.x * v.x + v.y * v.y + v.z * v.z + v.w * v.w;
#pragma unroll
    for (int off = 32; off; off >>= 1) sum += __shfl_xor(sum, off);
    const float scale = 1.0f / fmaxf(sqrtf(sum), 1e-12f);
    uint2 wv;
    wv.x = (unsigned)f2bf(v.x * scale) | ((unsigned)f2bf(v.y * scale) << 16);
    wv.y = (unsigned)f2bf(v.z * scale) | ((unsigned)f2bf(v.w * scale) << 16);
    *reinterpret_cast<uint2*>(&cn[(size_t)row * CCH + lane * 4]) = wv;
}

// ---------- fused MFMA GEMM + top-20 ----------
// grid (256 px-blocks, 4 slots); slot = 4096-cand slice of cn (0=fg, 1..3=bg thirds)
__global__ __launch_bounds__(256, 2) void score_kernel(
    const unsigned short* __restrict__ sn,   // [16384][256] bf16, normalized
    const unsigned short* __restrict__ cn,   // [16384][256] bf16, normalized
    float* __restrict__ partial)             // [4][16384][20]
{
    __shared__ __align__(16) unsigned short sA[64][256];    // A tile, chunk^(row&15)   32 KB
    __shared__ __align__(16) unsigned short sBuf[256][64];  // B chunk ^(cand&7) / sim  32 KB

    const int t    = threadIdx.x;
    const int w    = t >> 6;                  // wave 0..3 -> cand quadrant
    const int l    = t & 63;
    const int lm   = l & 15;
    const int lh   = l >> 4;
    const int p0   = blockIdx.x * BPX;
    const int slot = blockIdx.y;
    const size_t cbase = (size_t)slot * SLICE;

    // stage A once: 64 rows x 32 chunks of 16B, swizzled chunk^(row&15)
    {
        const int row = t >> 2, qg = t & 3;
        const uint4* g = reinterpret_cast<const uint4*>(&sn[(size_t)(p0 + row) * CCH]);
        uint4* d = reinterpret_cast<uint4*>(&sA[row][0]);
#pragma unroll
        for (int i = 0; i < 8; ++i) {
            int ch = qg * 8 + i;
            d[ch ^ (row & 15)] = g[ch];
        }
    }

    float lst[KTOP];
#pragma unroll
    for (int i = 0; i < KTOP; ++i) lst[i] = -1e30f;

    for (int nt = 0; nt < TILES; ++nt) {
        f32x4 acc[4][4];
#pragma unroll
        for (int m = 0; m < 4; ++m)
#pragma unroll
            for (int n = 0; n < 4; ++n) { f32x4 z = {0.f, 0.f, 0.f, 0.f}; acc[m][n] = z; }

        for (int ch = 0; ch < 4; ++ch) {
            __syncthreads();                 // prev MFMA/scan reads of sBuf done
            // stage B chunk: 256 cands x 64 ch bf16
            {
                const int c0 = ch * KC;
#pragma unroll
                for (int pass = 0; pass < 4; ++pass) {
                    int cand = pass * 64 + (t >> 2);
                    const uint4* g = reinterpret_cast<const uint4*>(
                        &cn[(cbase + (size_t)(nt * BCAND + cand)) * CCH + c0]);
                    uint4* d = reinterpret_cast<uint4*>(&sBuf[cand][0]);
#pragma unroll
                    for (int i = 0; i < 2; ++i) {
                        int cc = (t & 3) * 2 + i;
                        d[cc ^ (cand & 7)] = g[cc];
                    }
                }
            }
            __syncthreads();
#pragma unroll
            for (int k32 = 0; k32 < 2; ++k32) {
                short8 af[4], bfr[4];
#pragma unroll
                for (int m = 0; m < 4; ++m) {
                    int row = m * 16 + lm;
                    int chunk = ch * 8 + k32 * 4 + lh;
                    af[m] = *reinterpret_cast<const short8*>(&sA[row][(chunk ^ (row & 15)) * 8]);
                }
#pragma unroll
                for (int n = 0; n < 4; ++n) {
                    int cand = w * 64 + n * 16 + lm;
                    int cc = k32 * 4 + lh;
                    bfr[n] = *reinterpret_cast<const short8*>(&sBuf[cand][(cc ^ (cand & 7)) * 8]);
                }
#pragma unroll
                for (int m = 0; m < 4; ++m)
#pragma unroll
                    for (int n = 0; n < 4; ++n)
                        acc[m][n] = __builtin_amdgcn_mfma_f32_16x16x32_bf16(af[m], bfr[n], acc[m][n], 0, 0, 0);
            }
        }
        __syncthreads();                     // all sBuf B-reads done; safe to alias as sim
        // write sim [px][cand] fp16 per-wave region, chunk^(px&7)
        {
            _Float16* sim = reinterpret_cast<_Float16*>(&sBuf[0][0]) + w * 64 * 64;
#pragma unroll
            for (int m = 0; m < 4; ++m)
#pragma unroll
                for (int n = 0; n < 4; ++n)
#pragma unroll
                    for (int j = 0; j < 4; ++j) {
                        int px = m * 16 + lh * 4 + j;       // D row = (l>>4)*4 + j
                        int cand = n * 16 + lm;             // D col = l&15
                        int chunk = cand >> 3;
                        sim[px * 64 + ((chunk ^ (px & 7)) * 8) + (cand & 7)] =
                            (_Float16)acc[m][n][j];
                    }
        }
        __syncthreads();
        // scan: lane = pixel, wave's 64-cand quadrant
        {
            const _Float16* sim = reinterpret_cast<const _Float16*>(&sBuf[0][0]) + w * 64 * 64;
#pragma unroll
            for (int c8 = 0; c8 < 8; ++c8) {
                half8 hv = *reinterpret_cast<const half8*>(&sim[l * 64 + ((c8 ^ (l & 7)) * 8)]);
#pragma unroll
                for (int i = 0; i < 8; ++i) ins20(lst, (float)hv[i]);
            }
        }
    }

    // in-block merge of the 4 per-wave lists (alias sA; MFMA reads long done)
    __syncthreads();
    float* ml = reinterpret_cast<float*>(&sA[0][0]);        // [4][64][20]
#pragma unroll
    for (int i = 0; i < KTOP; ++i) ml[(w * 64 + l) * KTOP + i] = lst[i];
    __syncthreads();
    if (t < 64) {
        float fin[KTOP];
#pragma unroll
        for (int i = 0; i < KTOP; ++i) fin[i] = ml[t * KTOP + i];
        for (int ww = 1; ww < 4; ++ww) {
#pragma unroll
            for (int i = 0; i < KTOP; ++i) {
                float v = ml[(ww * 64 + t) * KTOP + i];
                if (v <= fin[KTOP - 1]) break;              // source sorted desc
                ins20(fin, v);
            }
        }
        float* dst = &partial[((size_t)slot * HW_N + p0 + t) * KTOP];
#pragma unroll
        for (int i = 0; i < KTOP; ++i) dst[i] = fin[i];
    }
}

// ---------- final cross-slot merge -> means ----------
__global__ void merge_kernel(const float* __restrict__ partial, float* __restrict__ out) {
    int idx  = blockIdx.x * blockDim.x + threadIdx.x;       // 0..32767
    int coll = idx >> 14;                                   // 0=fg, 1=bg
    int p    = idx & (HW_N - 1);
    float lst[KTOP];
#pragma unroll
    for (int i = 0; i < KTOP; ++i) lst[i] = -1e30f;
    int s0 = coll ? 1 : 0, s1 = coll ? 4 : 1;
    for (int sl = s0; sl < s1; ++sl) {
        const float* src = &partial[((size_t)sl * HW_N + p) * KTOP];
#pragma unroll
        for (int i = 0; i < KTOP; ++i) {
            float v = src[i];
            if (v <= lst[KTOP - 1]) break;                  // sorted desc
            ins20(lst, v);
        }
    }
    float sum = 0.f;
#pragma unroll
    for (int i = 0; i < KTOP; ++i) sum += lst[i];
    out[idx] = sum / (float)KTOP;
}

// ---------- launch ----------
extern "C" void kernel_launch(void* const* d_in, const int* in_sizes, int n_in,
                              void* d_out, int out_size, void* d_ws, size_t ws_size,
                              hipStream_t stream) {
    const float* s_feat = (const float*)d_in[0];   // [1,256,128,128]
    const float* fg     = (const float*)d_in[1];   // [4096,256]
    const float* bg     = (const float*)d_in[2];   // [12288,256]
    float* out = (float*)d_out;                    // [2][128][128]

    // ws: partial 5.24MB | sn 8.39MB | cn 8.39MB  (~22 MB total)
    float* partial     = (float*)d_ws;
    unsigned short* sn = (unsigned short*)(partial + (size_t)4 * HW_N * KTOP);
    unsigned short* cn = sn + (size_t)HW_N * CCH;

    s_prep_kernel<<<HW_N / 64, 256, 0, stream>>>(s_feat, sn);
    c_prep_kernel<<<NTOT / 4, 256, 0, stream>>>(fg, bg, cn);

    dim3 grid(HW_N / BPX, 4);
    score_kernel<<<grid, 256, 0, stream>>>(sn, cn, partial);

    merge_kernel<<<(2 * HW_N) / 256, 256, 0, stream>>>(partial, out);
}